// Round 8
// baseline (103.012 us; speedup 1.0000x reference)
//
#include <hip/hip_runtime.h>
#include <hip/hip_bf16.h>

// Problem constants
#define BB 32
#define DD 64
#define HW 1024
#define NN 32768   // BB*HW
#define MM 1024

typedef _Float16 half8 __attribute__((ext_vector_type(8)));
typedef float    floatx4 __attribute__((ext_vector_type(4)));

#define MFMA16(a, b, c) __builtin_amdgcn_mfma_f32_16x16x32_f16((a), (b), (c), 0, 0, 0)

// lo-term scaling to dodge fp16-denormal flush in the MFMA pipe
#define LO_SCALE   2048.0f
#define LO_INV     (1.0f / 2048.0f)

// async global->LDS copy, 16B per lane; LDS dest = wave-uniform base + lane*16
typedef __attribute__((address_space(1))) const void* gas_t;
typedef __attribute__((address_space(3)))       void* las_t;
#define ASYNC16(g, l) __builtin_amdgcn_global_load_lds((gas_t)(g), (las_t)(l), 16, 0, 0)

// ---------------------------------------------------------------------------
// Kernel 1 (prep): swizzle -2*codebook into MFMA B-frag order (fp16 hi/lo),
// compute codebook squared norms, zero the loss slot.  16 blocks x 512.
// B frag for mfma_f32_16x16x32_f16: B[k][n]: n=lane&15, k=(lane>>4)*8+j.
// Storage (half8 units): ch8[(mtile*2+kstep)*64 + lane]; cl = lo * 2048.
// ---------------------------------------------------------------------------
__global__ void k_prep(const float* __restrict__ cb,
                       _Float16* __restrict__ ch,
                       _Float16* __restrict__ cl,
                       float* __restrict__ y2,
                       float* __restrict__ loss_slot) {
    int u = blockIdx.x * blockDim.x + threadIdx.x;   // 0..8191
    if (u == 0) *loss_slot = 0.0f;

    if (u < 64 * 2 * 64) {
        int lane  = u & 63;
        int kstep = (u >> 6) & 1;
        int mtile = u >> 7;
        int m  = mtile * 16 + (lane & 15);
        int d0 = kstep * 32 + ((lane >> 4) & 3) * 8;
        const float* src = cb + (size_t)m * DD + d0;
        half8 h, l;
#pragma unroll
        for (int j = 0; j < 8; ++j) {
            float x = -2.0f * src[j];
            _Float16 hi = (_Float16)x;
            _Float16 lo = (_Float16)((x - (float)hi) * LO_SCALE);
            h[j] = hi;
            l[j] = lo;
        }
        *(half8*)(ch + (size_t)u * 8) = h;
        *(half8*)(cl + (size_t)u * 8) = l;
    }

    if (u < MM) {
        const float4* c4 = (const float4*)(cb + (size_t)u * DD);
        float s = 0.f;
#pragma unroll
        for (int k = 0; k < 16; ++k) {
            float4 v = c4[k];
            s += v.x * v.x + v.y * v.y + v.z * v.z + v.w * v.w;
        }
        y2[u] = s;
    }
}

// ---------------------------------------------------------------------------
// Kernel 2 (main): fused distance + argmin + q_error + z_q + loss.
// 256 blocks x 512 threads (8 waves).  Block = 128 rows (b = blk>>3,
// hw0 = (blk&7)<<7) -- double the row tile of rounds 3-7, halving B-traffic
// per unit work and doubling per-chunk compute (24 MFMA/wave/chunk).
// B streamed global->LDS via global_load_lds (zero staging VGPRs), double-
// buffered 4-mtile 16KB chunks, one barrier per chunk.
// Wave w: rh = w>>1 (2 ntiles = 32 rows of 128), mi = w&1 (2 mtiles/chunk;
// scans mt = 4c + 2mi + m2, strictly increasing).  LDS ~78KB -> 2 blocks/CU.
// Noise tile [64][129] overlays the B buffers after the main loop.
// Numerics: identical 6-MFMA sequence per (row,code), strict-< scan,
// idx-tie-broken merges -> bit-identical ind/z_q to all passing rounds.
// ---------------------------------------------------------------------------
__global__ __launch_bounds__(512) void k_main(const float* __restrict__ z,
                                              const float* __restrict__ noise,
                                              const _Float16* __restrict__ ch,
                                              const _Float16* __restrict__ cl,
                                              const float* __restrict__ y2,
                                              float* __restrict__ zq,
                                              float* __restrict__ ind_out,
                                              float* __restrict__ loss_slot) {
    __shared__ float zt[128][65];    // zt[row(hw)][d]   (33.3 KB)
    __shared__ float y2s[MM];
    __shared__ float x2p[128][4];
    __shared__ float snorm[128];
    __shared__ float scale_s[128];
    __shared__ float bestv_s[2][128]; // [mi group][row]
    __shared__ int   besti_s[2][128];
    __shared__ float partials[512];
    __shared__ float sq[8];
    // B double buffer (2 x 16KB = 32768 B) UNION noise tile float[64][129]
    // (33024 B, epilogue only)
    __shared__ __align__(16) char ubuf[33024];

    half8* bufB8 = (half8*)ubuf;
    float (*nt)[129] = (float (*)[129])ubuf;

    const int t    = threadIdx.x;
    const int lane = t & 63;
    const int wv   = t >> 6;            // wave 0..7
    const int mi   = wv & 1;            // mtile-pair-in-chunk
    const int rh   = wv >> 1;           // row quarter (32 rows)
    const int quad = lane >> 4;         // 0..3
    const int col  = lane & 15;         // 0..15
    const int blk  = blockIdx.x;        // 0..255
    const int b    = blk >> 3;
    const int hw0  = (blk & 7) << 7;

    const half8* ch8 = (const half8*)ch;
    const half8* cl8 = (const half8*)cl;

    // Async-copy job: chunk = 16KB = 1024 half8 = 16 jobs of 64 half8.
    // Wave wv does jobs 2wv, 2wv+1.  Jobs 0..7 = ch region, 8..15 = cl.
    const half8* gseg = (wv < 4) ? (ch8 + wv * 128) : (cl8 + (wv - 4) * 128);
    half8* l0 = bufB8 + wv * 128;          // buffer 0 dest (wave-uniform)
    half8* l1 = bufB8 + 1024 + wv * 128;   // buffer 1 dest

    // issue chunk-0 async loads immediately (latency overlaps z staging)
    ASYNC16(gseg + lane,      l0);
    ASYNC16(gseg + 64 + lane, l0 + 64);

    const float* zbase = z + ((size_t)b << 16) + hw0;

    // ---- stage z tile (coalesced) + y2 ----
    for (int i = t; i < 128 * 64; i += 512) {
        int d = i >> 7, r = i & 127;
        zt[r][d] = zbase[(size_t)d * HW + r];
    }
    for (int i = t; i < MM; i += 512) y2s[i] = y2[i];
    __syncthreads();   // zt ready; vmcnt(0) drain -> chunk 0 resident in LDS

    // ---- x2 partials + resident A fragments (hi/lo fp16), 2 ntiles ----
    {
        int row = t & 127, seg = t >> 7;       // 4 segments of 16 d
        float s = 0.f;
#pragma unroll
        for (int j = 0; j < 16; ++j) {
            float v = zt[row][seg * 16 + j];
            s = __builtin_fmaf(v, v, s);
        }
        x2p[row][seg] = s;
    }

    // A frag: A[m][k]: m=lane&15, k=(lane>>4)*8+j.
    half8 ah[2][2], al[2][2];
#pragma unroll
    for (int n2 = 0; n2 < 2; ++n2) {
        int row = rh * 32 + n2 * 16 + col;
#pragma unroll
        for (int ks = 0; ks < 2; ++ks) {
            int d0 = ks * 32 + quad * 8;
            half8 h, l;
#pragma unroll
            for (int j = 0; j < 8; ++j) {
                float x = zt[row][d0 + j];
                _Float16 hi = (_Float16)x;
                _Float16 lo = (_Float16)((x - (float)hi) * LO_SCALE);
                h[j] = hi;
                l[j] = lo;
            }
            ah[n2][ks] = h;
            al[n2][ks] = l;
        }
    }

    // ---- main loop: 16 chunks, async double-buffer, 1 barrier/chunk ----
    float best[8];
    int   bmt[8];
#pragma unroll
    for (int s = 0; s < 8; ++s) { best[s] = 1e30f; bmt[s] = 0; }

#pragma unroll 2
    for (int c = 0; c < 16; ++c) {
        const int p = c & 1;
        if (c) __syncthreads();   // chunk c loads done; buffer 1-p free

        if (c < 15) {             // issue async loads for chunk c+1
            const half8* gs = gseg + (c + 1) * 512;
            half8* ls = ((c + 1) & 1) ? l1 : l0;
            ASYNC16(gs + lane,      ls);
            ASYNC16(gs + 64 + lane, ls + 64);
        }

        const half8* bp = bufB8 + p * 1024;

#pragma unroll
        for (int m2 = 0; m2 < 2; ++m2) {
            const int ml = mi * 2 + m2;           // mtile-local in chunk
            half8 bh0 = bp[(ml * 2 + 0) * 64 + lane];
            half8 bh1 = bp[(ml * 2 + 1) * 64 + lane];
            half8 bl0 = bp[512 + (ml * 2 + 0) * 64 + lane];
            half8 bl1 = bp[512 + (ml * 2 + 1) * 64 + lane];

            const int mt = c * 4 + ml;
            float y2v = y2s[(mt << 4) + col];
            floatx4 a1[2], a2[2];
#pragma unroll
            for (int n2 = 0; n2 < 2; ++n2) {
                floatx4 i1 = {y2v, y2v, y2v, y2v};
                floatx4 i2 = {0.f, 0.f, 0.f, 0.f};
                a1[n2] = i1;
                a2[n2] = i2;
            }
#pragma unroll
            for (int n2 = 0; n2 < 2; ++n2) {
                a1[n2] = MFMA16(ah[n2][0], bh0, a1[n2]);   // hi*hi (k 0..31)
                a2[n2] = MFMA16(al[n2][0], bh0, a2[n2]);   // lo*hi
                a2[n2] = MFMA16(ah[n2][0], bl0, a2[n2]);   // hi*lo
                a1[n2] = MFMA16(ah[n2][1], bh1, a1[n2]);   // hi*hi (k 32..63)
                a2[n2] = MFMA16(al[n2][1], bh1, a2[n2]);
                a2[n2] = MFMA16(ah[n2][1], bl1, a2[n2]);
            }
#pragma unroll
            for (int n2 = 0; n2 < 2; ++n2) {
#pragma unroll
                for (int r = 0; r < 4; ++r) {
                    float v = __builtin_fmaf(a2[n2][r], LO_INV, a1[n2][r]);
                    int s = n2 * 4 + r;
                    bool cc = v < best[s];
                    best[s] = cc ? v : best[s];
                    bmt[s]  = cc ? mt : bmt[s];
                }
            }
        }
    }
    __syncthreads();   // all waves done with bufB -> safe to overlay nt

    // ---- noise tile load into overlay + row norms (overlaps argmin VALU) ----
    {
        const float4* noise4 = (const float4*)noise;
        const size_t base4 = (size_t)blk * 2048;     // 8192 floats / 4
#pragma unroll
        for (int k = 0; k < 4; ++k) {
            int v = t + 512 * k;                     // float4 index [0,2048)
            float4 vv = noise4[base4 + v];
            int c  = v >> 4;                         // row in tile [0,128)
            int d0 = (v & 15) << 2;
            nt[d0 + 0][c] = vv.x;
            nt[d0 + 1][c] = vv.y;
            nt[d0 + 2][c] = vv.z;
            nt[d0 + 3][c] = vv.w;
            float p = vv.x * vv.x + vv.y * vv.y + vv.z * vv.z + vv.w * vv.w;
            p += __shfl_xor(p, 1);
            p += __shfl_xor(p, 2);
            p += __shfl_xor(p, 4);
            p += __shfl_xor(p, 8);
            if ((t & 15) == 0) snorm[c] = p;
        }
    }

    // ---- per-wave cross-lane argmin (16 lanes share a row), then LDS ----
#pragma unroll
    for (int n2 = 0; n2 < 2; ++n2) {
#pragma unroll
        for (int r = 0; r < 4; ++r) {
            int s = n2 * 4 + r;
            float v  = best[s];
            int  idx = bmt[s] * 16 + col;
#pragma unroll
            for (int mask = 1; mask <= 8; mask <<= 1) {
                float v2 = __shfl_xor(v, mask);
                int   i2 = __shfl_xor(idx, mask);
                if (v2 < v || (v2 == v && i2 < idx)) { v = v2; idx = i2; }
            }
            if (col == 0) {
                int rl = rh * 32 + n2 * 16 + quad * 4 + r;
                bestv_s[mi][rl] = v;
                besti_s[mi][rl] = idx;
            }
        }
    }
    __syncthreads();

    // ---- merge mi-groups; write ind; compute scale in LDS ----
    if (t < 128) {
        float bv = bestv_s[0][t];
        int   bi = besti_s[0][t];
        {
            float v = bestv_s[1][t];
            int   ix = besti_s[1][t];
            if (v < bv || (v == bv && ix < bi)) { bv = v; bi = ix; }
        }
        float x2 = x2p[t][0] + x2p[t][1] + x2p[t][2] + x2p[t][3];
        float dm = x2 + bv;
        int n = (blk << 7) + t;
        ind_out[n] = (float)bi;
        float nr = fmaxf(sqrtf(snorm[t]), 1e-9f);
        scale_s[t] = sqrtf(fmaxf(dm, 0.f)) / nr;
    }
    __syncthreads();

    // ---- z_q write (coalesced, z from LDS) + loss partials ----
    float acc = 0.f;
    const size_t obase = ((size_t)b << 16) + hw0;
#pragma unroll
    for (int it = 0; it < 16; ++it) {
        int flat = it * 512 + t;
        int d = flat >> 7;               // wave-uniform
        int c = flat & 127;
        float v = zt[c][d] + nt[d][c] * scale_s[c];
        zq[obase + (size_t)d * HW + c] = v;
        acc += v;
    }

    partials[t] = acc;   // thread's c = t&127 fixed -> one 16-row group
    __syncthreads();
    if (t < 8) {
        float s = 0.f;
        for (int cp = 0; cp < 4; ++cp)          // 4 thread-copies per c
            for (int j = 0; j < 16; ++j)
                s += partials[cp * 128 + t * 16 + j];
        sq[t] = s * s;
    }
    __syncthreads();
    if (t == 0) {
        float c8 = 0.f;
#pragma unroll
        for (int g = 0; g < 8; ++g) c8 += sq[g];
        atomicAdd(loss_slot, c8 * (1.0f / 33554432.0f));
    }
}

// ---------------------------------------------------------------------------
extern "C" void kernel_launch(void* const* d_in, const int* in_sizes, int n_in,
                              void* d_out, int out_size, void* d_ws, size_t ws_size,
                              hipStream_t stream) {
    const float* z        = (const float*)d_in[0];   // (32,64,32,32)
    const float* codebook = (const float*)d_in[1];   // (1024,64)
    const float* noise    = (const float*)d_in[2];   // (32768,64)

    float* out      = (float*)d_out;
    float* zq_out   = out;                 // 2097152 floats
    float* loss_ptr = out + 2097152;       // 1 float
    float* ind_out  = out + 2097153;       // 32768 floats

    float* y2       = (float*)d_ws;             // 1024 floats
    _Float16* ch    = (_Float16*)(y2 + MM);     // 65536 halves (128KB)
    _Float16* cl    = ch + 65536;               // 65536 halves (128KB)

    k_prep<<<16,  512, 0, stream>>>(codebook, ch, cl, y2, loss_ptr);
    k_main<<<256, 512, 0, stream>>>(z, noise, ch, cl, y2,
                                    zq_out, ind_out, loss_ptr);
}